// Round 22
// baseline (36.487 us; speedup 1.0000x reference)
//
#include <hip/hip_runtime.h>
#include <hip/hip_fp16.h>
#include <math.h>

// B=8, C=64, H=W=64, O=128, K=3, N=9, stride=1, pad=1
// ws layout (12.8 MB):
//   xTh   @ 0         : fp16 hi(x)  [8][4096 pix][64 c] = 4,194,304 B
//   xTl   @ 4194304   : fp16 lo(x)  [8][4096 pix][64 c] = 4,194,304 B
//   xCb   @ 8388608   : fp16 (x[p]+2x[p+1]) [8][4096][64] = 4,194,304 B
//   WtF   @ 12582912  : fp16 main W in MFMA-fragment order  = 147,456 B
//   WtSFh @ 12730368  : fp16 stage1 W hi, fragment order    =  36,864 B
//   WtSFl @ 12767232  : fp16 stage1 W lo, fragment order    =  36,864 B

typedef _Float16 half8_t __attribute__((ext_vector_type(8)));
typedef float f32x4 __attribute__((ext_vector_type(4)));

// ---------------------------------------------------------------------------
// k_pre v3: transpose split 4x along c (2048 blocks of 16c x 64pix) vs v2's
//   1024 blocks of 32c. Tile 4.2KB -> high blocks/CU, 4 reads + 3x8B stores
//   per thread. Same math bit-for-bit.
//   blocks 0..2047: x -> xTh/xTl/xCb ; blocks 2048..2407: W fragment tables
// ---------------------------------------------------------------------------
__global__ __launch_bounds__(256) void k_pre(const float* __restrict__ x,
                                             const float* __restrict__ cw,
                                             const float* __restrict__ shift_w,
                                             const float* __restrict__ mod_w,
                                             __half* __restrict__ xTh,
                                             __half* __restrict__ xTl,
                                             __half* __restrict__ xCb,
                                             __half* __restrict__ WtF,
                                             __half* __restrict__ WtSFh,
                                             __half* __restrict__ WtSFl) {
    __shared__ float tile[16][65];
    int bid = blockIdx.x;
    int t = threadIdx.x;
    if (bid < 2048) {
        int b = bid >> 8;
        int pt = (bid >> 2) & 63;          // image row
        int cq4 = bid & 3;                 // c-quarter (16 c each)
        int lane = t & 63, cg4 = t >> 6;   // cg4 0..3 -> 4 c each
        const float* xb = x + ((size_t)b << 18) + ((size_t)cq4 << 16);
#pragma unroll
        for (int r = 0; r < 4; ++r) {
            int c = cg4 * 4 + r;           // local c 0..15
            tile[c][lane] = xb[((size_t)c << 12) + pt * 64 + lane];
        }
        __syncthreads();
        int p = t >> 2, qc = t & 3;        // p = pixel 0..63, qc -> 4 c each
        __align__(8) _Float16 hh[4];
        __align__(8) _Float16 ll[4];
        __align__(8) _Float16 cb[4];
#pragma unroll
        for (int k = 0; k < 4; ++k) {
            int c = qc * 4 + k;
            float v0 = tile[c][p];
            float v1 = (p < 63) ? tile[c][p + 1] : 0.f;   // col63 cb unused
            _Float16 h = (_Float16)v0;
            hh[k] = h;
            ll[k] = (_Float16)(v0 - (float)h);
            cb[k] = (_Float16)(v0 + 2.f * v1);            // degenerate bilinear
        }
        size_t off = ((size_t)b << 18) + (size_t)(pt * 64 + p) * 64 +
                     (cq4 << 4) + (qc << 2);
        *(uint2*)(xTh + off) = *(uint2*)hh;
        *(uint2*)(xTl + off) = *(uint2*)ll;
        *(uint2*)(xCb + off) = *(uint2*)cb;
    } else {
        int u = (bid - 2048) * 256 + t;
        if (u < 73728) {
            int e = u & 7, l = (u >> 3) & 63, ks = (u >> 9) & 1;
            int g = (u >> 10) & 3, w = (u >> 12) & 1, n = u >> 13;
            int o = w * 64 + g * 16 + (l & 15);
            int c = ks * 32 + (l >> 4) * 8 + e;
            WtF[u] = __float2half_rn(cw[(o * 64 + c) * 9 + n]);
        } else {
            int q = u - 73728;
            if (q < 18432) {
                int e = q & 7, l = (q >> 3) & 63, nf = (q >> 9) & 1;
                int chf = (q >> 10) & 1, tap = q >> 11;
                int chn = nf * 16 + (l & 15);
                int c = chf * 32 + (l >> 4) * 8 + e;
                float wv = 0.f;
                if (chn < 18) wv = shift_w[(chn * 64 + c) * 9 + tap];
                else if (chn < 27) wv = mod_w[((chn - 18) * 64 + c) * 9 + tap];
                _Float16 h = (_Float16)wv;
                _Float16 lo = (_Float16)(wv - (float)h);
                WtSFh[q] = *(__half*)&h;
                WtSFl[q] = *(__half*)&lo;
            }
        }
    }
}

// ---------------------------------------------------------------------------
// combine helper: gathers + record -> A fragment (8 fp16)
// ---------------------------------------------------------------------------
__device__ __forceinline__ void combine_frag(uint4 rc, bool simple, float mod,
                                             const uint4& g0, const uint4& g1,
                                             const uint4& g2, const uint4& g3,
                                             __half2* a2) {
    if (simple) {
        __half mh = __float2half_rn(mod);
        __half2 mm(mh, mh);
        const __half2* vv = (const __half2*)&g0;
        a2[0] = __hmul2(mm, vv[0]);
        a2[1] = __hmul2(mm, vv[1]);
        a2[2] = __hmul2(mm, vv[2]);
        a2[3] = __hmul2(mm, vv[3]);
    } else {
        a2[0] = __half2(0, 0); a2[1] = __half2(0, 0);
        a2[2] = __half2(0, 0); a2[3] = __half2(0, 0);
        const uint4* grs[4] = {&g0, &g1, &g2, &g3};
#pragma unroll
        for (int jq = 0; jq < 4; ++jq) {
            float wf = (float)((rc.x >> (24 + 2 * jq)) & 3) * mod;
            __half2 wh2 = __half2(__float2half_rn(wf), __float2half_rn(wf));
            const __half2* vv = (const __half2*)grs[jq];
            a2[0] = __hfma2(wh2, vv[0], a2[0]);
            a2[1] = __hfma2(wh2, vv[1], a2[1]);
            a2[2] = __hfma2(wh2, vv[2], a2[2]);
            a2[3] = __hfma2(wh2, vv[3], a2[3]);
        }
    }
}

// ---------------------------------------------------------------------------
// k_fused (R20-verbatim, session best): 64 pix x 128 o, 8 waves,
//   2 blocks/CU (LDS+VGPR-bound); phase B 2-deep pipeline + lgkm-only soft bar.
// ---------------------------------------------------------------------------
__global__ __launch_bounds__(512, 2) void k_fused(
    const __half* __restrict__ xTh, const __half* __restrict__ xTl,
    const __half* __restrict__ xCb, const __half* __restrict__ WtF,
    const __half* __restrict__ WtSFh, const __half* __restrict__ WtSFl,
    const float* __restrict__ shift_b, const float* __restrict__ mod_b,
    float* __restrict__ out) {
    // arena: stage: tileH @0 (25344), tileL @25344 (25344)
    //        phase B: A slabs @0,@8192 (8KB each); W slabs @16384,@32768 (16KB each)
    //        epilogue: Ep f32[128][65] @0 (33280), after final tap barrier
    __shared__ __align__(16) unsigned char arena[50688];
    __shared__ float Cw[2][4][16][36];   // [wh][wp][pix16][ch(36)]
    __shared__ uint4 recA[9][64];

    int t = threadIdx.x;
    int l = t & 63;
    int w = t >> 6;                       // 8 waves
    int l15 = l & 15, lhi = l >> 4;

    // XCD swizzle: 512 = 8 XCD x 64; each XCD gets one batch image.
    int bid = blockIdx.x;
    int bk = (bid & 7) * 64 + (bid >> 3);
    int b = bk >> 6;
    int row = bk & 63;

    const __half* xbh = xTh + ((size_t)b << 18);
    const __half* xbl = xTl + ((size_t)b << 18);
    const __half* xbc = xCb + ((size_t)b << 18);

    // ---------------- stage halo tile: 3 rows x 66 cols, h+l ----------------
#pragma unroll
    for (int rr = 0; rr < 7; ++rr) {
        int d = rr * 512 + t;
        if (d < 3168) {
            int bufl = d >= 1584 ? 1 : 0;
            int dd = d - bufl * 1584;
            int s = dd >> 3, cb8 = dd & 7;   // slot s (198), 16B chunk cb8
            int r = s / 66, j = s - r * 66;
            int grow = row + r - 1;
            int gcol = j - 1;
            uint4 v = make_uint4(0u, 0u, 0u, 0u);
            if ((unsigned)grow < 64u && (unsigned)gcol < 64u) {
                const __half* src = (bufl ? xbl : xbh) +
                                    ((size_t)((grow << 6) + gcol) << 6) + (cb8 << 3);
                v = *(const uint4*)src;
            }
            int dst = bufl * 25344 + s * 128 + ((cb8 << 4) ^ ((s & 7) << 4));
            *(uint4*)&arena[dst] = v;
        }
    }
    __syncthreads();

    // ---------------- Phase A: wave (wp = w>>1 in 0..3, wh = w&1) -------------
    {
        int wp = w >> 1, wh = w & 1;
        f32x4 accA[2];
        accA[0] = (f32x4){0.f, 0.f, 0.f, 0.f};
        accA[1] = (f32x4){0.f, 0.f, 0.f, 0.f};
#pragma unroll
        for (int tr = 0; tr < 3; ++tr)
#pragma unroll
            for (int tc = 0; tc < 3; ++tc) {
                int tap = tr * 3 + tc;
                int j = wp * 16 + l15 + tc;      // tile col 0..65
                int s = tr * 66 + j;
                int cbyte = (wh << 6) + (lhi << 4);
                int addr = s * 128 + (cbyte ^ ((s & 7) << 4));
                half8_t Ah = *(const half8_t*)&arena[addr];
                half8_t Al = *(const half8_t*)&arena[25344 + addr];
#pragma unroll
                for (int nf = 0; nf < 2; ++nf) {
                    int fo = ((((tap << 1) + wh) << 1) + nf) << 9;
                    half8_t Bh = *(const half8_t*)(WtSFh + fo + (l << 3));
                    half8_t Bl = *(const half8_t*)(WtSFl + fo + (l << 3));
                    accA[nf] = __builtin_amdgcn_mfma_f32_16x16x32_f16(Ah, Bh, accA[nf], 0, 0, 0);
                    accA[nf] = __builtin_amdgcn_mfma_f32_16x16x32_f16(Ah, Bl, accA[nf], 0, 0, 0);
                    accA[nf] = __builtin_amdgcn_mfma_f32_16x16x32_f16(Al, Bh, accA[nf], 0, 0, 0);
                }
            }
#pragma unroll
        for (int nf = 0; nf < 2; ++nf)
#pragma unroll
            for (int v4 = 0; v4 < 4; ++v4)
                Cw[wh][wp][(lhi << 2) + v4][nf * 16 + l15] = accA[nf][v4];
    }
    __syncthreads();

    // ---------------- records: 64 pix x 9 n (+ simple flag) ----------------
#pragma unroll
    for (int jj0 = 0; jj0 < 2; ++jj0) {
        int rid = jj0 * 512 + t;
        if (rid < 576) {
            int p = rid & 63;
            int n = rid >> 6;
            int wp = p >> 4, pp = p & 15;
            float sx = Cw[0][wp][pp][n] + Cw[1][wp][pp][n];
            float sy = Cw[0][wp][pp][9 + n] + Cw[1][wp][pp][9 + n];
            float sm = Cw[0][wp][pp][18 + n] + Cw[1][wp][pp][18 + n];

            float px = ((sx + shift_b[n]) + (float)(n / 3 - 1)) + (float)(row + 1);
            float py = ((sy + shift_b[9 + n]) + (float)(n % 3 - 1)) + (float)(p + 1);
            float mod = 1.f / (1.f + expf(-(sm + mod_b[n])));

            float fx = floorf(px), fy = floorf(py);
            int ltx = (int)fminf(fmaxf(fx, 0.f), 63.f);
            int lty = (int)fminf(fmaxf(fy, 0.f), 63.f);
            int rbx = (int)fminf(fmaxf(fx + 1.f, 0.f), 63.f);
            int rby = (int)fminf(fmaxf(fy + 1.f, 0.f), 63.f);
            int pxi = (int)fminf(fmaxf(px, 0.f), 63.f);
            int pyi = (int)fminf(fmaxf(py, 0.f), 63.f);

            int g_lt = (1 + ltx - pxi) * (1 + lty - pyi);
            int g_rb = (1 - rbx + pxi) * (1 - rby + pyi);
            int g_lb = (1 + ltx - pxi) * (1 + rby - pyi);
            int g_rt = (1 - rbx + pxi) * (1 - lty + pyi);

            bool simple = (ltx == pxi) && (lty == pyi) && (rbx == pxi + 1) &&
                          (rby == pyi + 1) && (ltx >= 1) && (lty >= 1);

            int qxa[4] = {ltx, rbx, ltx, rbx};
            int qya[4] = {lty, rby, rby, lty};
            int gga[4] = {g_lt, g_rb, g_lb, g_rt};
            unsigned w0 = 0, w1 = 0;
#pragma unroll
            for (int jq = 0; jq < 4; ++jq) {
                bool valid = (qxa[jq] >= 1) && (qya[jq] >= 1);
                unsigned idx = valid ? (unsigned)((qxa[jq] - 1) * 64 + (qya[jq] - 1)) : 0u;
                unsigned gc = valid ? (unsigned)gga[jq] : 0u;   // 0..2
                if (jq < 2) w0 |= idx << (12 * jq); else w1 |= idx << (12 * (jq - 2));
                w0 |= gc << (24 + 2 * jq);
            }
            if (simple) w1 |= 0x80000000u;
            recA[n][p] = make_uint4(w0, w1, __float_as_uint(mod), 0u);
        }
    }
    __syncthreads();

    // ---------------- Phase B: 9 taps, 2-deep pipeline + soft barriers -------
    int wm = w >> 1, wn = w & 1;        // wm 0..3 (pixel 16-group), wn 0..1 (o-half)
    int mA = t >> 3, cg = t & 7;        // A-build task: pixel mA (0..63), c-chunk cg

    f32x4 acc[4];
#pragma unroll
    for (int g = 0; g < 4; ++g) acc[g] = (f32x4){0.f, 0.f, 0.f, 0.f};

#define ISSUE(W0, W1, RC, SMP, G0, G1, G2, G3, nn)                             \
    {                                                                          \
        const uint4* wsrc_ = (const uint4*)(WtF + (nn) * 8192);                \
        W0 = wsrc_[t];                                                         \
        W1 = wsrc_[512 + t];                                                   \
        RC = recA[nn][mA];                                                     \
        SMP = (RC.y >> 31) != 0u;                                              \
        if (SMP) {                                                             \
            G0 = *(const uint4*)(xbc + ((int)(RC.x & 0xFFF) << 6) + (cg << 3));\
        } else {                                                               \
            G0 = *(const uint4*)(xbh + ((int)(RC.x & 0xFFF) << 6) + (cg << 3));\
            G1 = *(const uint4*)(xbh + ((int)((RC.x >> 12) & 0xFFF) << 6) + (cg << 3)); \
            G2 = *(const uint4*)(xbh + ((int)(RC.y & 0xFFF) << 6) + (cg << 3));\
            G3 = *(const uint4*)(xbh + ((int)((RC.y >> 12) & 0xFFF) << 6) + (cg << 3)); \
        }                                                                      \
    }

#define WRITE_SLAB(W0, W1, RC, SMP, G0, G1, G2, G3, slot)                      \
    {                                                                          \
        uint4* wdst_ = (uint4*)&arena[16384 + ((slot) << 14)];                 \
        wdst_[t] = W0;                                                         \
        wdst_[512 + t] = W1;                                                   \
        __align__(16) __half2 a2_[4];                                          \
        combine_frag(RC, SMP, __uint_as_float(RC.z), G0, G1, G2, G3, a2_);     \
        *(uint4*)&arena[((slot) << 13) | (mA << 7) | ((cg ^ (mA & 7)) << 4)] = \
            *(uint4*)a2_;                                                      \
    }

    // soft barrier: LDS-visibility only; in-flight VMEM prefetch NOT drained
#define SOFT_BAR()                                                             \
    {                                                                          \
        asm volatile("s_waitcnt lgkmcnt(0)" ::: "memory");                     \
        __builtin_amdgcn_s_barrier();                                          \
        __builtin_amdgcn_sched_barrier(0);                                     \
    }

    // registers for two pipeline stages
    uint4 wA0, wA1, rcA_, gA0, gA1, gA2, gA3;
    uint4 wB0, wB1, rcB_, gB0, gB1, gB2, gB3;
    bool smA = false, smB = false;

    // prologue: stage tap 0 into slab 0; issue tap 1 into set A
    ISSUE(wA0, wA1, rcA_, smA, gA0, gA1, gA2, gA3, 0);
    WRITE_SLAB(wA0, wA1, rcA_, smA, gA0, gA1, gA2, gA3, 0);
    ISSUE(wA0, wA1, rcA_, smA, gA0, gA1, gA2, gA3, 1);
    SOFT_BAR();

#pragma unroll
    for (int n = 0; n < 9; ++n) {
        int sl = n & 1;

        // 1) issue tap n+2's loads into set B (full iteration of latency cover)
        if (n < 7) {
            ISSUE(wB0, wB1, rcB_, smB, gB0, gB1, gB2, gB3, n + 2);
        }

        // 2) MFMA tap n: A slab sl, W slab sl
        {
            const unsigned char* wsl = &arena[16384 + (sl << 14)];
#pragma unroll
            for (int ks = 0; ks < 2; ++ks) {
                int rowa = wm * 16 + l15;
                int gr = (ks * 4 + lhi) ^ (rowa & 7);
                half8_t Af = *(const half8_t*)&arena[(sl << 13) | (rowa << 7) | (gr << 4)];
#pragma unroll
                for (int g = 0; g < 4; ++g) {
                    half8_t Bf = *(const half8_t*)&wsl[((((wn << 2) + g) << 1) + ks) * 1024 +
                                                       (l << 4)];
                    acc[g] = __builtin_amdgcn_mfma_f32_16x16x32_f16(Af, Bf, acc[g], 0, 0, 0);
                }
            }
        }

        // 3) combine + write tap n+1 (set A, loaded a full iteration ago)
        if (n < 8) {
            WRITE_SLAB(wA0, wA1, rcA_, smA, gA0, gA1, gA2, gA3, sl ^ 1);
        }

        // 4) rotate B -> A (static; loop fully unrolled)
        if (n < 7) {
            wA0 = wB0; wA1 = wB1; rcA_ = rcB_; smA = smB;
            gA0 = gB0; gA1 = gB1; gA2 = gB2; gA3 = gB3;
        }
        SOFT_BAR();
    }
#undef ISSUE
#undef WRITE_SLAB
#undef SOFT_BAR

    // ---------------- Epilogue: one-shot Ep f32[128][65] ----------------
    // (loop-final barrier above synchronized all MFMA arena reads)
    float* Ep = (float*)arena;
#pragma unroll
    for (int g = 0; g < 4; ++g) {
        int o_loc = (wn << 6) + (g << 4) + l15;
#pragma unroll
        for (int v4 = 0; v4 < 4; ++v4)
            Ep[o_loc * 65 + (wm << 4) + (lhi << 2) + v4] = acc[g][v4];
    }
    __syncthreads();
    {
        float* ob = out + ((size_t)b << 19);
        int prow = row << 6;
#pragma unroll
        for (int r = 0; r < 4; ++r) {
            int o_loc = (r << 5) + (t >> 4);   // 0..127
            int mseg = t & 15;                 // 0..15 -> 64 pix
            float4 fa;
            fa.x = Ep[o_loc * 65 + mseg * 4 + 0];
            fa.y = Ep[o_loc * 65 + mseg * 4 + 1];
            fa.z = Ep[o_loc * 65 + mseg * 4 + 2];
            fa.w = Ep[o_loc * 65 + mseg * 4 + 3];
            float* dst = ob + (((size_t)o_loc) << 12) + prow + mseg * 4;
            *(float4*)dst = fa;
        }
    }
}

// ---------------------------------------------------------------------------
extern "C" void kernel_launch(void* const* d_in, const int* in_sizes, int n_in,
                              void* d_out, int out_size, void* d_ws, size_t ws_size,
                              hipStream_t stream) {
    const float* x = (const float*)d_in[0];
    const float* shift_w = (const float*)d_in[1];
    const float* shift_b = (const float*)d_in[2];
    const float* mod_w = (const float*)d_in[3];
    const float* mod_b = (const float*)d_in[4];
    const float* conv_w = (const float*)d_in[5];
    float* out = (float*)d_out;

    char* ws = (char*)d_ws;
    __half* xTh = (__half*)ws;                         // 4 MB
    __half* xTl = (__half*)(ws + 4194304);             // 4 MB
    __half* xCb = (__half*)(ws + 8388608);             // 4 MB
    __half* WtF = (__half*)(ws + 12582912);            // 144 KB
    __half* WtSFh = (__half*)(ws + 12730368);          // 36 KB
    __half* WtSFl = (__half*)(ws + 12767232);          // 36 KB  (total 12.8 MB)

    k_pre<<<dim3(2408), dim3(256), 0, stream>>>(x, conv_w, shift_w, mod_w,
                                                xTh, xTl, xCb, WtF, WtSFh, WtSFl);
    k_fused<<<dim3(512), dim3(512), 0, stream>>>(xTh, xTl, xCb, WtF, WtSFh,
                                                 WtSFl, shift_b, mod_b, out);
}

// Round 23
// 33.021 us; speedup vs baseline: 1.1050x; 1.1050x over previous
//
#include <hip/hip_runtime.h>
#include <hip/hip_fp16.h>
#include <math.h>

// B=8, C=64, H=W=64, O=128, K=3, N=9, stride=1, pad=1
// ws layout (12.8 MB):
//   xTh   @ 0         : fp16 hi(x)  [8][4096 pix][64 c] = 4,194,304 B
//   xTl   @ 4194304   : fp16 lo(x)  [8][4096 pix][64 c] = 4,194,304 B
//   xCb   @ 8388608   : fp16 (x[p]+2x[p+1]) [8][4096][64] = 4,194,304 B
//   WtF   @ 12582912  : fp16 main W in MFMA-fragment order  = 147,456 B
//   WtSFh @ 12730368  : fp16 stage1 W hi, fragment order    =  36,864 B
//   WtSFl @ 12767232  : fp16 stage1 W lo, fragment order    =  36,864 B

typedef _Float16 half8_t __attribute__((ext_vector_type(8)));
typedef float f32x4 __attribute__((ext_vector_type(4)));

// ---------------------------------------------------------------------------
// k_pre (R21-validated optimum): transpose split 2x along c (1024 blocks of
//   32c x 64pix, 16B stores); blocks 1024..1383: W fragment tables
// ---------------------------------------------------------------------------
__global__ __launch_bounds__(256) void k_pre(const float* __restrict__ x,
                                             const float* __restrict__ cw,
                                             const float* __restrict__ shift_w,
                                             const float* __restrict__ mod_w,
                                             __half* __restrict__ xTh,
                                             __half* __restrict__ xTl,
                                             __half* __restrict__ xCb,
                                             __half* __restrict__ WtF,
                                             __half* __restrict__ WtSFh,
                                             __half* __restrict__ WtSFl) {
    __shared__ float tile[32][65];
    int bid = blockIdx.x;
    int t = threadIdx.x;
    if (bid < 1024) {
        int b = bid >> 7;
        int pt = (bid >> 1) & 63;          // image row
        int ch = bid & 1;                  // c-half (0: c 0..31, 1: c 32..63)
        int lane = t & 63, cq = t >> 6;    // cq 0..3
        const float* xb = x + ((size_t)b << 18) + ((size_t)ch << 17);
#pragma unroll
        for (int r = 0; r < 8; ++r) {
            int c = cq * 8 + r;            // local c 0..31
            tile[c][lane] = xb[((size_t)c << 12) + pt * 64 + lane];
        }
        __syncthreads();
        int p = t >> 2, qc = t & 3;        // p = pixel 0..63, qc -> 8 c each
        __align__(16) _Float16 hh[8];
        __align__(16) _Float16 ll[8];
        __align__(16) _Float16 cb[8];
#pragma unroll
        for (int k = 0; k < 8; ++k) {
            int c = qc * 8 + k;
            float v0 = tile[c][p];
            float v1 = (p < 63) ? tile[c][p + 1] : 0.f;   // col63 cb unused
            _Float16 h = (_Float16)v0;
            hh[k] = h;
            ll[k] = (_Float16)(v0 - (float)h);
            cb[k] = (_Float16)(v0 + 2.f * v1);            // degenerate bilinear
        }
        size_t off = ((size_t)b << 18) + (size_t)(pt * 64 + p) * 64 +
                     (ch << 5) + (qc << 3);
        *(uint4*)(xTh + off) = *(uint4*)hh;
        *(uint4*)(xTl + off) = *(uint4*)ll;
        *(uint4*)(xCb + off) = *(uint4*)cb;
    } else {
        int u = (bid - 1024) * 256 + t;
        if (u < 73728) {
            int e = u & 7, l = (u >> 3) & 63, ks = (u >> 9) & 1;
            int g = (u >> 10) & 3, w = (u >> 12) & 1, n = u >> 13;
            int o = w * 64 + g * 16 + (l & 15);
            int c = ks * 32 + (l >> 4) * 8 + e;
            WtF[u] = __float2half_rn(cw[(o * 64 + c) * 9 + n]);
        } else {
            int q = u - 73728;
            if (q < 18432) {
                int e = q & 7, l = (q >> 3) & 63, nf = (q >> 9) & 1;
                int chf = (q >> 10) & 1, tap = q >> 11;
                int chn = nf * 16 + (l & 15);
                int c = chf * 32 + (l >> 4) * 8 + e;
                float wv = 0.f;
                if (chn < 18) wv = shift_w[(chn * 64 + c) * 9 + tap];
                else if (chn < 27) wv = mod_w[((chn - 18) * 64 + c) * 9 + tap];
                _Float16 h = (_Float16)wv;
                _Float16 lo = (_Float16)(wv - (float)h);
                WtSFh[q] = *(__half*)&h;
                WtSFl[q] = *(__half*)&lo;
            }
        }
    }
}

// ---------------------------------------------------------------------------
// combine helper: gathers + record -> A fragment (8 fp16)
// ---------------------------------------------------------------------------
__device__ __forceinline__ void combine_frag(uint4 rc, bool simple, float mod,
                                             const uint4& g0, const uint4& g1,
                                             const uint4& g2, const uint4& g3,
                                             __half2* a2) {
    if (simple) {
        __half mh = __float2half_rn(mod);
        __half2 mm(mh, mh);
        const __half2* vv = (const __half2*)&g0;
        a2[0] = __hmul2(mm, vv[0]);
        a2[1] = __hmul2(mm, vv[1]);
        a2[2] = __hmul2(mm, vv[2]);
        a2[3] = __hmul2(mm, vv[3]);
    } else {
        a2[0] = __half2(0, 0); a2[1] = __half2(0, 0);
        a2[2] = __half2(0, 0); a2[3] = __half2(0, 0);
        const uint4* grs[4] = {&g0, &g1, &g2, &g3};
#pragma unroll
        for (int jq = 0; jq < 4; ++jq) {
            float wf = (float)((rc.x >> (24 + 2 * jq)) & 3) * mod;
            __half2 wh2 = __half2(__float2half_rn(wf), __float2half_rn(wf));
            const __half2* vv = (const __half2*)grs[jq];
            a2[0] = __hfma2(wh2, vv[0], a2[0]);
            a2[1] = __hfma2(wh2, vv[1], a2[1]);
            a2[2] = __hfma2(wh2, vv[2], a2[2]);
            a2[3] = __hfma2(wh2, vv[3], a2[3]);
        }
    }
}

// ---------------------------------------------------------------------------
// k_fused (R20-verbatim, session best): 64 pix x 128 o, 8 waves,
//   2 blocks/CU (LDS+VGPR-bound); phase B 2-deep pipeline + lgkm-only soft bar.
// ---------------------------------------------------------------------------
__global__ __launch_bounds__(512, 2) void k_fused(
    const __half* __restrict__ xTh, const __half* __restrict__ xTl,
    const __half* __restrict__ xCb, const __half* __restrict__ WtF,
    const __half* __restrict__ WtSFh, const __half* __restrict__ WtSFl,
    const float* __restrict__ shift_b, const float* __restrict__ mod_b,
    float* __restrict__ out) {
    // arena: stage: tileH @0 (25344), tileL @25344 (25344)
    //        phase B: A slabs @0,@8192 (8KB each); W slabs @16384,@32768 (16KB each)
    //        epilogue: Ep f32[128][65] @0 (33280), after final tap barrier
    __shared__ __align__(16) unsigned char arena[50688];
    __shared__ float Cw[2][4][16][36];   // [wh][wp][pix16][ch(36)]
    __shared__ uint4 recA[9][64];

    int t = threadIdx.x;
    int l = t & 63;
    int w = t >> 6;                       // 8 waves
    int l15 = l & 15, lhi = l >> 4;

    // XCD swizzle: 512 = 8 XCD x 64; each XCD gets one batch image.
    int bid = blockIdx.x;
    int bk = (bid & 7) * 64 + (bid >> 3);
    int b = bk >> 6;
    int row = bk & 63;

    const __half* xbh = xTh + ((size_t)b << 18);
    const __half* xbl = xTl + ((size_t)b << 18);
    const __half* xbc = xCb + ((size_t)b << 18);

    // ---------------- stage halo tile: 3 rows x 66 cols, h+l ----------------
#pragma unroll
    for (int rr = 0; rr < 7; ++rr) {
        int d = rr * 512 + t;
        if (d < 3168) {
            int bufl = d >= 1584 ? 1 : 0;
            int dd = d - bufl * 1584;
            int s = dd >> 3, cb8 = dd & 7;   // slot s (198), 16B chunk cb8
            int r = s / 66, j = s - r * 66;
            int grow = row + r - 1;
            int gcol = j - 1;
            uint4 v = make_uint4(0u, 0u, 0u, 0u);
            if ((unsigned)grow < 64u && (unsigned)gcol < 64u) {
                const __half* src = (bufl ? xbl : xbh) +
                                    ((size_t)((grow << 6) + gcol) << 6) + (cb8 << 3);
                v = *(const uint4*)src;
            }
            int dst = bufl * 25344 + s * 128 + ((cb8 << 4) ^ ((s & 7) << 4));
            *(uint4*)&arena[dst] = v;
        }
    }
    __syncthreads();

    // ---------------- Phase A: wave (wp = w>>1 in 0..3, wh = w&1) -------------
    {
        int wp = w >> 1, wh = w & 1;
        f32x4 accA[2];
        accA[0] = (f32x4){0.f, 0.f, 0.f, 0.f};
        accA[1] = (f32x4){0.f, 0.f, 0.f, 0.f};
#pragma unroll
        for (int tr = 0; tr < 3; ++tr)
#pragma unroll
            for (int tc = 0; tc < 3; ++tc) {
                int tap = tr * 3 + tc;
                int j = wp * 16 + l15 + tc;      // tile col 0..65
                int s = tr * 66 + j;
                int cbyte = (wh << 6) + (lhi << 4);
                int addr = s * 128 + (cbyte ^ ((s & 7) << 4));
                half8_t Ah = *(const half8_t*)&arena[addr];
                half8_t Al = *(const half8_t*)&arena[25344 + addr];
#pragma unroll
                for (int nf = 0; nf < 2; ++nf) {
                    int fo = ((((tap << 1) + wh) << 1) + nf) << 9;
                    half8_t Bh = *(const half8_t*)(WtSFh + fo + (l << 3));
                    half8_t Bl = *(const half8_t*)(WtSFl + fo + (l << 3));
                    accA[nf] = __builtin_amdgcn_mfma_f32_16x16x32_f16(Ah, Bh, accA[nf], 0, 0, 0);
                    accA[nf] = __builtin_amdgcn_mfma_f32_16x16x32_f16(Ah, Bl, accA[nf], 0, 0, 0);
                    accA[nf] = __builtin_amdgcn_mfma_f32_16x16x32_f16(Al, Bh, accA[nf], 0, 0, 0);
                }
            }
#pragma unroll
        for (int nf = 0; nf < 2; ++nf)
#pragma unroll
            for (int v4 = 0; v4 < 4; ++v4)
                Cw[wh][wp][(lhi << 2) + v4][nf * 16 + l15] = accA[nf][v4];
    }
    __syncthreads();

    // ---------------- records: 64 pix x 9 n (+ simple flag) ----------------
#pragma unroll
    for (int jj0 = 0; jj0 < 2; ++jj0) {
        int rid = jj0 * 512 + t;
        if (rid < 576) {
            int p = rid & 63;
            int n = rid >> 6;
            int wp = p >> 4, pp = p & 15;
            float sx = Cw[0][wp][pp][n] + Cw[1][wp][pp][n];
            float sy = Cw[0][wp][pp][9 + n] + Cw[1][wp][pp][9 + n];
            float sm = Cw[0][wp][pp][18 + n] + Cw[1][wp][pp][18 + n];

            float px = ((sx + shift_b[n]) + (float)(n / 3 - 1)) + (float)(row + 1);
            float py = ((sy + shift_b[9 + n]) + (float)(n % 3 - 1)) + (float)(p + 1);
            float mod = 1.f / (1.f + expf(-(sm + mod_b[n])));

            float fx = floorf(px), fy = floorf(py);
            int ltx = (int)fminf(fmaxf(fx, 0.f), 63.f);
            int lty = (int)fminf(fmaxf(fy, 0.f), 63.f);
            int rbx = (int)fminf(fmaxf(fx + 1.f, 0.f), 63.f);
            int rby = (int)fminf(fmaxf(fy + 1.f, 0.f), 63.f);
            int pxi = (int)fminf(fmaxf(px, 0.f), 63.f);
            int pyi = (int)fminf(fmaxf(py, 0.f), 63.f);

            int g_lt = (1 + ltx - pxi) * (1 + lty - pyi);
            int g_rb = (1 - rbx + pxi) * (1 - rby + pyi);
            int g_lb = (1 + ltx - pxi) * (1 + rby - pyi);
            int g_rt = (1 - rbx + pxi) * (1 - lty + pyi);

            bool simple = (ltx == pxi) && (lty == pyi) && (rbx == pxi + 1) &&
                          (rby == pyi + 1) && (ltx >= 1) && (lty >= 1);

            int qxa[4] = {ltx, rbx, ltx, rbx};
            int qya[4] = {lty, rby, rby, lty};
            int gga[4] = {g_lt, g_rb, g_lb, g_rt};
            unsigned w0 = 0, w1 = 0;
#pragma unroll
            for (int jq = 0; jq < 4; ++jq) {
                bool valid = (qxa[jq] >= 1) && (qya[jq] >= 1);
                unsigned idx = valid ? (unsigned)((qxa[jq] - 1) * 64 + (qya[jq] - 1)) : 0u;
                unsigned gc = valid ? (unsigned)gga[jq] : 0u;   // 0..2
                if (jq < 2) w0 |= idx << (12 * jq); else w1 |= idx << (12 * (jq - 2));
                w0 |= gc << (24 + 2 * jq);
            }
            if (simple) w1 |= 0x80000000u;
            recA[n][p] = make_uint4(w0, w1, __float_as_uint(mod), 0u);
        }
    }
    __syncthreads();

    // ---------------- Phase B: 9 taps, 2-deep pipeline + soft barriers -------
    int wm = w >> 1, wn = w & 1;        // wm 0..3 (pixel 16-group), wn 0..1 (o-half)
    int mA = t >> 3, cg = t & 7;        // A-build task: pixel mA (0..63), c-chunk cg

    f32x4 acc[4];
#pragma unroll
    for (int g = 0; g < 4; ++g) acc[g] = (f32x4){0.f, 0.f, 0.f, 0.f};

#define ISSUE(W0, W1, RC, SMP, G0, G1, G2, G3, nn)                             \
    {                                                                          \
        const uint4* wsrc_ = (const uint4*)(WtF + (nn) * 8192);                \
        W0 = wsrc_[t];                                                         \
        W1 = wsrc_[512 + t];                                                   \
        RC = recA[nn][mA];                                                     \
        SMP = (RC.y >> 31) != 0u;                                              \
        if (SMP) {                                                             \
            G0 = *(const uint4*)(xbc + ((int)(RC.x & 0xFFF) << 6) + (cg << 3));\
        } else {                                                               \
            G0 = *(const uint4*)(xbh + ((int)(RC.x & 0xFFF) << 6) + (cg << 3));\
            G1 = *(const uint4*)(xbh + ((int)((RC.x >> 12) & 0xFFF) << 6) + (cg << 3)); \
            G2 = *(const uint4*)(xbh + ((int)(RC.y & 0xFFF) << 6) + (cg << 3));\
            G3 = *(const uint4*)(xbh + ((int)((RC.y >> 12) & 0xFFF) << 6) + (cg << 3)); \
        }                                                                      \
    }

#define WRITE_SLAB(W0, W1, RC, SMP, G0, G1, G2, G3, slot)                      \
    {                                                                          \
        uint4* wdst_ = (uint4*)&arena[16384 + ((slot) << 14)];                 \
        wdst_[t] = W0;                                                         \
        wdst_[512 + t] = W1;                                                   \
        __align__(16) __half2 a2_[4];                                          \
        combine_frag(RC, SMP, __uint_as_float(RC.z), G0, G1, G2, G3, a2_);     \
        *(uint4*)&arena[((slot) << 13) | (mA << 7) | ((cg ^ (mA & 7)) << 4)] = \
            *(uint4*)a2_;                                                      \
    }

    // soft barrier: LDS-visibility only; in-flight VMEM prefetch NOT drained
#define SOFT_BAR()                                                             \
    {                                                                          \
        asm volatile("s_waitcnt lgkmcnt(0)" ::: "memory");                     \
        __builtin_amdgcn_s_barrier();                                          \
        __builtin_amdgcn_sched_barrier(0);                                     \
    }

    // registers for two pipeline stages
    uint4 wA0, wA1, rcA_, gA0, gA1, gA2, gA3;
    uint4 wB0, wB1, rcB_, gB0, gB1, gB2, gB3;
    bool smA = false, smB = false;

    // prologue: stage tap 0 into slab 0; issue tap 1 into set A
    ISSUE(wA0, wA1, rcA_, smA, gA0, gA1, gA2, gA3, 0);
    WRITE_SLAB(wA0, wA1, rcA_, smA, gA0, gA1, gA2, gA3, 0);
    ISSUE(wA0, wA1, rcA_, smA, gA0, gA1, gA2, gA3, 1);
    SOFT_BAR();

#pragma unroll
    for (int n = 0; n < 9; ++n) {
        int sl = n & 1;

        // 1) issue tap n+2's loads into set B (full iteration of latency cover)
        if (n < 7) {
            ISSUE(wB0, wB1, rcB_, smB, gB0, gB1, gB2, gB3, n + 2);
        }

        // 2) MFMA tap n: A slab sl, W slab sl
        {
            const unsigned char* wsl = &arena[16384 + (sl << 14)];
#pragma unroll
            for (int ks = 0; ks < 2; ++ks) {
                int rowa = wm * 16 + l15;
                int gr = (ks * 4 + lhi) ^ (rowa & 7);
                half8_t Af = *(const half8_t*)&arena[(sl << 13) | (rowa << 7) | (gr << 4)];
#pragma unroll
                for (int g = 0; g < 4; ++g) {
                    half8_t Bf = *(const half8_t*)&wsl[((((wn << 2) + g) << 1) + ks) * 1024 +
                                                       (l << 4)];
                    acc[g] = __builtin_amdgcn_mfma_f32_16x16x32_f16(Af, Bf, acc[g], 0, 0, 0);
                }
            }
        }

        // 3) combine + write tap n+1 (set A, loaded a full iteration ago)
        if (n < 8) {
            WRITE_SLAB(wA0, wA1, rcA_, smA, gA0, gA1, gA2, gA3, sl ^ 1);
        }

        // 4) rotate B -> A (static; loop fully unrolled)
        if (n < 7) {
            wA0 = wB0; wA1 = wB1; rcA_ = rcB_; smA = smB;
            gA0 = gB0; gA1 = gB1; gA2 = gB2; gA3 = gB3;
        }
        SOFT_BAR();
    }
#undef ISSUE
#undef WRITE_SLAB
#undef SOFT_BAR

    // ---------------- Epilogue: one-shot Ep f32[128][65] ----------------
    // (loop-final barrier above synchronized all MFMA arena reads)
    float* Ep = (float*)arena;
#pragma unroll
    for (int g = 0; g < 4; ++g) {
        int o_loc = (wn << 6) + (g << 4) + l15;
#pragma unroll
        for (int v4 = 0; v4 < 4; ++v4)
            Ep[o_loc * 65 + (wm << 4) + (lhi << 2) + v4] = acc[g][v4];
    }
    __syncthreads();
    {
        float* ob = out + ((size_t)b << 19);
        int prow = row << 6;
#pragma unroll
        for (int r = 0; r < 4; ++r) {
            int o_loc = (r << 5) + (t >> 4);   // 0..127
            int mseg = t & 15;                 // 0..15 -> 64 pix
            float4 fa;
            fa.x = Ep[o_loc * 65 + mseg * 4 + 0];
            fa.y = Ep[o_loc * 65 + mseg * 4 + 1];
            fa.z = Ep[o_loc * 65 + mseg * 4 + 2];
            fa.w = Ep[o_loc * 65 + mseg * 4 + 3];
            float* dst = ob + (((size_t)o_loc) << 12) + prow + mseg * 4;
            *(float4*)dst = fa;
        }
    }
}

// ---------------------------------------------------------------------------
extern "C" void kernel_launch(void* const* d_in, const int* in_sizes, int n_in,
                              void* d_out, int out_size, void* d_ws, size_t ws_size,
                              hipStream_t stream) {
    const float* x = (const float*)d_in[0];
    const float* shift_w = (const float*)d_in[1];
    const float* shift_b = (const float*)d_in[2];
    const float* mod_w = (const float*)d_in[3];
    const float* mod_b = (const float*)d_in[4];
    const float* conv_w = (const float*)d_in[5];
    float* out = (float*)d_out;

    char* ws = (char*)d_ws;
    __half* xTh = (__half*)ws;                         // 4 MB
    __half* xTl = (__half*)(ws + 4194304);             // 4 MB
    __half* xCb = (__half*)(ws + 8388608);             // 4 MB
    __half* WtF = (__half*)(ws + 12582912);            // 144 KB
    __half* WtSFh = (__half*)(ws + 12730368);          // 36 KB
    __half* WtSFl = (__half*)(ws + 12767232);          // 36 KB  (total 12.8 MB)

    k_pre<<<dim3(1384), dim3(256), 0, stream>>>(x, conv_w, shift_w, mod_w,
                                                xTh, xTl, xCb, WtF, WtSFh, WtSFl);
    k_fused<<<dim3(512), dim3(512), 0, stream>>>(xTh, xTl, xCb, WtF, WtSFh,
                                                 WtSFl, shift_b, mod_b, out);
}